// Round 13
// baseline (39.653 us; speedup 1.0000x reference)
//
#include <hip/hip_runtime.h>
#include <math.h>
#include <utility>

// EPG simulation, one thread per pixel, register-resident (R4 structure —
// best measured: 20.4us, bit-identical arithmetic). Probe: WG-dispatch
// overhead — same 4096 waves / 4 per SIMD, but 512-thread blocks -> 512 WGs
// (half of R4's 1024). __launch_bounds__(512,4) pins VGPR<=128.
// NOTE (R12 lesson): do NOT divide by E2 — T2 can be ~0.01 so E2=exp(-1500)
// underflows to 0.0f; rcp(E2)=inf -> NaN. Echo computed directly pre-scale.
//
// State invariant: F+ = i*fp, F- = i*fm (pure imaginary), Z real.
// Double-sided band: rotation band A(t) = min(t, KMAX, 31-t)
//   forward:  slots > t are still exactly 0 (never touched)
//   backward: slot k entering step t only influences echoes t' >= t+k
// Per step:
//   echo_t = |c2*fp0 + s2*fm0 - sa*z0|      (PD pre-folded into state)
//   Rp = Aa*fp + Bb*fm + Cc*z ; Rm = Bb*fp + Aa*fm - Cc*z
//   Zn = Ez*z + Dd*(fp - fm)
//   shift: fp[k]=Rp[k-1] (k>=1), fp[0]=Rm[1] (S[0:2,4]=1 quirk);
//          fm[k]=Rm[k+1]; z=Zn; z[0]+=inj
// with Aa=-E2*c2, Bb=-E2*s2, Cc=E2*sa, Dd=E1*sa/2, Ez=E1*ca, inj=(1-E1)*PD.
// Echoes buffered in 4-reg ring -> one global_store_dwordx4 per 4 steps.

#define NPULSES 32
#define KK 18
#define KMAX 17

__host__ __device__ constexpr int cmin3(int a, int b, int c) {
    int m = a < b ? a : b; return m < c ? m : c;
}

template <typename F, int... Ts>
__device__ __forceinline__ void static_for(F&& f, std::integer_sequence<int, Ts...>) {
    (f(std::integral_constant<int, Ts>{}), ...);
}

__global__ __launch_bounds__(512, 4) void epg_kernel(
    const float* __restrict__ qm,   // (3, npix) flattened
    const int* __restrict__ tr_ptr, // scalar TR
    float* __restrict__ out,        // (npix, 32)
    int npix)
{
    const int p = blockIdx.x * 512 + threadIdx.x;
    if (p >= npix) return;

    float PD = qm[p];
    float T1 = fmaf(qm[npix + p], 5000.0f, 0.01f);
    float T2 = fmaf(qm[2 * npix + p], 1500.0f, 0.01f);
    float TR = (float)(*tr_ptr);
    float E1 = __expf(-TR / T1);
    float E2 = __expf(-TR / T2);

    // RF rotation constants, alpha = pi/4, phi = 0
    const float c2 = 0.8535533905932737f;   // cos^2(pi/8)
    const float s2 = 0.1464466094067263f;   // sin^2(pi/8)
    const float sa = 0.7071067811865476f;   // sin(pi/4) == cos(pi/4)

    float Aa = -E2 * c2;
    float Bb = -E2 * s2;
    float Cc =  E2 * sa;
    float Dd =  E1 * 0.5f * sa;
    float Ez =  E1 * sa;                    // E1*cos(alpha), ca == sa
    float inj = (1.0f - E1) * PD;           // PD folded into state scale

    float fp[KK], fm[KK], z[KK];
    #pragma unroll
    for (int k = 0; k < KK; ++k) { fp[k] = 0.0f; fm[k] = 0.0f; z[k] = 0.0f; }
    z[0] = PD;

    float4* o4 = (float4*)(out + (size_t)p * NPULSES);
    float ebuf[4];

    static_for([&](auto tc) {
        constexpr int t = decltype(tc)::value;
        constexpr int A = cmin3(t, KMAX, (NPULSES - 1) - t);   // rotation band

        // echo: unscaled rotated F+_0 magnitude (E2/conj not folded in)
        float e = fmaf(c2, fp[0], fmaf(s2, fm[0], -sa * z[0]));
        ebuf[t & 3] = fabsf(e);
        if constexpr ((t & 3) == 3)
            o4[t >> 2] = make_float4(ebuf[0], ebuf[1], ebuf[2], ebuf[3]);

        if constexpr (t < NPULSES - 1) {
            constexpr int B = cmin3(t + 1, KMAX, (NPULSES - 2) - t); // next band

            // zero-top-padded temporaries: index A+1 is a genuine zero slot
            float Rp[A + 2], Rm[A + 2], Zn[A + 2];
            Rm[A + 1] = 0.0f; Zn[A + 1] = 0.0f;
            #pragma unroll
            for (int k = 0; k <= A; ++k) {
                float pk = fp[k], mk = fm[k], zk = z[k];
                float Cz = Cc * zk;
                Rp[k] = fmaf(Aa, pk, fmaf(Bb, mk,  Cz));
                Rm[k] = fmaf(Bb, pk, fmaf(Aa, mk, -Cz));
                Zn[k] = fmaf(Ez, zk, Dd * (pk - mk));
            }

            // shift into next-state band (quirk: fp[0], fm[0] both get Rm[1])
            #pragma unroll
            for (int k = B; k >= 1; --k) fp[k] = Rp[k - 1];
            fp[0] = Rm[1];
            #pragma unroll
            for (int k = 0; k <= B; ++k) fm[k] = (k <= A) ? Rm[k + 1] : 0.0f;
            #pragma unroll
            for (int k = 0; k <= B; ++k) z[k] = Zn[k];
            z[0] += inj;
        }
    }, std::make_integer_sequence<int, NPULSES>{});
}

extern "C" void kernel_launch(void* const* d_in, const int* in_sizes, int n_in,
                              void* d_out, int out_size, void* d_ws, size_t ws_size,
                              hipStream_t stream) {
    const float* qm = (const float*)d_in[0];
    const int* tr = (const int*)d_in[2];   // d_in[1] = n_pulses (compile-time 32)
    float* out = (float*)d_out;
    int npix = in_sizes[0] / 3;

    int block = 512;
    int grid = (npix + block - 1) / block;
    epg_kernel<<<grid, block, 0, stream>>>(qm, tr, out, npix);
}

// Round 14
// 22.270 us; speedup vs baseline: 1.7806x; 1.7806x over previous
//
#include <hip/hip_runtime.h>
#include <math.h>
#include <utility>

// EPG simulation, one thread per pixel, register-resident (R4 structure —
// best measured: 20.4us, bit-identical arithmetic). Probe: WG-dispatch
// overhead with CORRECT occupancy pinning.
// R13 lesson [measured]: hipcc __launch_bounds__ arg2 acts as CUDA-style
// min-BLOCKS-per-CU: (512,4) -> 32 waves/CU -> VGPR cap 64 -> 86MB spill
// traffic, 44us. Here (512,2): 2 blocks/CU x 8 waves = 16 waves/CU =
// 4 waves/SIMD, VGPR cap 128 — same budget/occupancy as R4's 256-thread
// config, but HALF the workgroups (512 vs 1024).
// R12 lesson: never divide by E2 (underflows to 0 for small T2 -> NaN).
//
// State invariant: F+ = i*fp, F- = i*fm (pure imaginary), Z real.
// Double-sided band: rotation band A(t) = min(t, KMAX, 31-t)
//   forward:  slots > t are still exactly 0 (never touched)
//   backward: slot k entering step t only influences echoes t' >= t+k
// Per step:
//   echo_t = |c2*fp0 + s2*fm0 - sa*z0|      (PD pre-folded into state)
//   Rp = Aa*fp + Bb*fm + Cc*z ; Rm = Bb*fp + Aa*fm - Cc*z
//   Zn = Ez*z + Dd*(fp - fm)
//   shift: fp[k]=Rp[k-1] (k>=1), fp[0]=Rm[1] (S[0:2,4]=1 quirk);
//          fm[k]=Rm[k+1]; z=Zn; z[0]+=inj
// with Aa=-E2*c2, Bb=-E2*s2, Cc=E2*sa, Dd=E1*sa/2, Ez=E1*ca, inj=(1-E1)*PD.
// Echoes buffered in 4-reg ring -> one global_store_dwordx4 per 4 steps.

#define NPULSES 32
#define KK 18
#define KMAX 17

__host__ __device__ constexpr int cmin3(int a, int b, int c) {
    int m = a < b ? a : b; return m < c ? m : c;
}

template <typename F, int... Ts>
__device__ __forceinline__ void static_for(F&& f, std::integer_sequence<int, Ts...>) {
    (f(std::integral_constant<int, Ts>{}), ...);
}

__global__ __launch_bounds__(512, 2) void epg_kernel(
    const float* __restrict__ qm,   // (3, npix) flattened
    const int* __restrict__ tr_ptr, // scalar TR
    float* __restrict__ out,        // (npix, 32)
    int npix)
{
    const int p = blockIdx.x * 512 + threadIdx.x;
    if (p >= npix) return;

    float PD = qm[p];
    float T1 = fmaf(qm[npix + p], 5000.0f, 0.01f);
    float T2 = fmaf(qm[2 * npix + p], 1500.0f, 0.01f);
    float TR = (float)(*tr_ptr);
    float E1 = __expf(-TR / T1);
    float E2 = __expf(-TR / T2);

    // RF rotation constants, alpha = pi/4, phi = 0
    const float c2 = 0.8535533905932737f;   // cos^2(pi/8)
    const float s2 = 0.1464466094067263f;   // sin^2(pi/8)
    const float sa = 0.7071067811865476f;   // sin(pi/4) == cos(pi/4)

    float Aa = -E2 * c2;
    float Bb = -E2 * s2;
    float Cc =  E2 * sa;
    float Dd =  E1 * 0.5f * sa;
    float Ez =  E1 * sa;                    // E1*cos(alpha), ca == sa
    float inj = (1.0f - E1) * PD;           // PD folded into state scale

    float fp[KK], fm[KK], z[KK];
    #pragma unroll
    for (int k = 0; k < KK; ++k) { fp[k] = 0.0f; fm[k] = 0.0f; z[k] = 0.0f; }
    z[0] = PD;

    float4* o4 = (float4*)(out + (size_t)p * NPULSES);
    float ebuf[4];

    static_for([&](auto tc) {
        constexpr int t = decltype(tc)::value;
        constexpr int A = cmin3(t, KMAX, (NPULSES - 1) - t);   // rotation band

        // echo: unscaled rotated F+_0 magnitude (E2/conj not folded in)
        float e = fmaf(c2, fp[0], fmaf(s2, fm[0], -sa * z[0]));
        ebuf[t & 3] = fabsf(e);
        if constexpr ((t & 3) == 3)
            o4[t >> 2] = make_float4(ebuf[0], ebuf[1], ebuf[2], ebuf[3]);

        if constexpr (t < NPULSES - 1) {
            constexpr int B = cmin3(t + 1, KMAX, (NPULSES - 2) - t); // next band

            // zero-top-padded temporaries: index A+1 is a genuine zero slot
            float Rp[A + 2], Rm[A + 2], Zn[A + 2];
            Rm[A + 1] = 0.0f; Zn[A + 1] = 0.0f;
            #pragma unroll
            for (int k = 0; k <= A; ++k) {
                float pk = fp[k], mk = fm[k], zk = z[k];
                float Cz = Cc * zk;
                Rp[k] = fmaf(Aa, pk, fmaf(Bb, mk,  Cz));
                Rm[k] = fmaf(Bb, pk, fmaf(Aa, mk, -Cz));
                Zn[k] = fmaf(Ez, zk, Dd * (pk - mk));
            }

            // shift into next-state band (quirk: fp[0], fm[0] both get Rm[1])
            #pragma unroll
            for (int k = B; k >= 1; --k) fp[k] = Rp[k - 1];
            fp[0] = Rm[1];
            #pragma unroll
            for (int k = 0; k <= B; ++k) fm[k] = (k <= A) ? Rm[k + 1] : 0.0f;
            #pragma unroll
            for (int k = 0; k <= B; ++k) z[k] = Zn[k];
            z[0] += inj;
        }
    }, std::make_integer_sequence<int, NPULSES>{});
}

extern "C" void kernel_launch(void* const* d_in, const int* in_sizes, int n_in,
                              void* d_out, int out_size, void* d_ws, size_t ws_size,
                              hipStream_t stream) {
    const float* qm = (const float*)d_in[0];
    const int* tr = (const int*)d_in[2];   // d_in[1] = n_pulses (compile-time 32)
    float* out = (float*)d_out;
    int npix = in_sizes[0] / 3;

    int block = 512;
    int grid = (npix + block - 1) / block;
    epg_kernel<<<grid, block, 0, stream>>>(qm, tr, out, npix);
}